// Round 5
// baseline (267.514 us; speedup 1.0000x reference)
//
#include <hip/hip_runtime.h>
#include <hip/hip_bf16.h>
#include <hip/hip_fp16.h>

// RecursiveNN forest bottom-up pass, fp32 in / fp32 out.
// forest_kernel: one block per EIGHTH-tree (64 level-1 pair-rows).
// Round-4 lesson: barrier-drain fixed but forest still ~66 us, occupancy-
// limited (~1.6 blocks/CU avg). This version deletes the LDS leaf Arena:
// phase-1 MFMA A-fragments are loaded DIRECTLY from global fp32 leaves
// (per-wave pattern is fully coalesced: q-pairs share 64-B lines) with
// on-the-fly f16 conversion. Effects: no serial preload chain, phase-1
// global-read->LDS-write provably no-alias (compiler pipelines all 4
// chunks), LDS 53.5 -> 18.7 KB so residency is VGPR-capped at 4 blocks/CU.
//   - phase 1 (level 1, 4 chunks): ZERO barriers (per-wave column slices)
//   - level-1 proj split across 4 waves, direct to out
//   - phase 2 (levels 2..7): in-place halving, lgkm-only barriers;
//     proj -> LDS outbox, flushed coalesced at kernel end
// prep converts W/P to f16 once. rnn_top: top 3 levels fp32 (verified).

typedef _Float16 f16_t;
typedef _Float16 f16x4 __attribute__((ext_vector_type(4)));
typedef _Float16 f16x8 __attribute__((ext_vector_type(8)));
typedef float f32x4 __attribute__((ext_vector_type(4)));

#define HSTRIDE 136   // f16 elems per row slot: 272 B, 16B-aligned

static __device__ __forceinline__ f32x4 mfma16(f16x8 a, f16x8 b, f32x4 c) {
    return __builtin_amdgcn_mfma_f32_16x16x32_f16(a, b, c, 0, 0, 0);
}

static __device__ __forceinline__ f16x8 cvt8(const float* p) {
    const float4 a = *(const float4*)p;
    const float4 b = *(const float4*)(p + 4);
    f16x8 t = { (f16_t)a.x, (f16_t)a.y, (f16_t)a.z, (f16_t)a.w,
                (f16_t)b.x, (f16_t)b.y, (f16_t)b.z, (f16_t)b.w };
    return t;
}

// One-shot: W [128,256] fp32 -> fp16 Wh; P [5,128] fp32 -> fp16 Ph.
__global__ void prep_kernel(const float* __restrict__ W, const float* __restrict__ P,
                            f16_t* __restrict__ Wh, f16_t* __restrict__ Ph) {
    if (blockIdx.x < 128) {
        const int i = blockIdx.x * 256 + threadIdx.x;
        Wh[i] = (f16_t)W[i];
    } else {
        for (int i = threadIdx.x; i < 640; i += 256) Ph[i] = (f16_t)P[i];
    }
}

// ---------------- fused levels 1..7 for one 64-pair-row eighth-tree ----------------
__global__ __launch_bounds__(256, 2)
void forest_kernel(const float* __restrict__ leaves,
                   const f16_t* __restrict__ Wh,
                   const f16_t* __restrict__ Ph,
                   const float* __restrict__ bW,
                   const float* __restrict__ bP,
                   f16_t* __restrict__ Q,          // [2048,128] eighth-roots
                   float* __restrict__ out)
{
    __shared__ f16_t Hbuf[64 * HSTRIDE];         // 17408 B frontier, in-place halving
    __shared__ float OutB[320];                  // 1280 B proj outbox (levels 2..7)

    const int tid   = threadIdx.x;
    const int wave  = tid >> 6;
    const int lane  = tid & 63;
    const int mlane = lane & 15;
    const int q     = lane >> 4;
    const int tree  = blockIdx.x >> 3;
    const int e     = blockIdx.x & 7;
    const size_t m0 = (size_t)blockIdx.x * 64;   // global level-1 pair-row base
    const float* leafbase = leaves + (size_t)blockIdx.x * 16384;

    // W b-frags (gemm_bt, verified): lane holds W[col][k*32 + q*8 + e]
    f16x8 wh[2][8];
    float bwv[2];
    #pragma unroll
    for (int n = 0; n < 2; ++n) {
        const int col = wave * 32 + n * 16 + mlane;
        bwv[n] = bW[col];
        #pragma unroll
        for (int k = 0; k < 8; ++k)
            wh[n][k] = *(const f16x8*)&Wh[col * 256 + k * 32 + q * 8];
    }

    // P b-frags, N padded 5->16 (zero rows for mlane>=5)
    f16x8 pb[4] = {};
    if (mlane < 5) {
        #pragma unroll
        for (int kb = 0; kb < 4; ++kb)
            pb[kb] = *(const f16x8*)&Ph[mlane * 128 + kb * 32 + q * 8];
    }
    const float bpv = (mlane < 5) ? bP[mlane] : 0.f;

    // ---- phase 1: level 1, 4 chunks, NO barriers, A-frags direct from global ----
    // leaf row = 32c + 2*mlane + trow, float col = ce; 32-B loads, q-pairs
    // share 64-B lines -> fully coalesced per wave.
    #pragma unroll
    for (int c = 0; c < 4; ++c) {
        f16x8 af[8];
        #pragma unroll
        for (int k = 0; k < 8; ++k) {
            const int off  = k * 64 + q * 16;    // byte offset in 512B pair-row (f16 view)
            const int trow = off >> 8;
            const int ce   = (off & 255) >> 1;   // float col within 128-float leaf row
            af[k] = cvt8(&leafbase[(32 * c + 2 * mlane + trow) * 128 + ce]);
        }
        f32x4 acc0 = {}, acc1 = {};
        #pragma unroll
        for (int k = 0; k < 8; ++k) {
            acc0 = mfma16(af[k], wh[0][k], acc0);
            acc1 = mfma16(af[k], wh[1][k], acc1);
        }
        #pragma unroll
        for (int r = 0; r < 4; ++r) {
            float v0 = fmaxf(acc0[r] + bwv[0], 0.f);
            float v1 = fmaxf(acc1[r] + bwv[1], 0.f);
            Hbuf[(c * 16 + q * 4 + r) * HSTRIDE + wave * 32 + mlane]      = (f16_t)v0;
            Hbuf[(c * 16 + q * 4 + r) * HSTRIDE + wave * 32 + 16 + mlane] = (f16_t)v1;
        }
    }
    __syncthreads();                             // Hbuf rows 0..63 complete

    // ---- level-1 proj: each wave projects its own 16 rows, direct to out ----
    {
        const int hrow0 = wave * 16;
        f32x4 pc = {};
        #pragma unroll
        for (int kb = 0; kb < 4; ++kb) {
            const f16x8 ha = *(const f16x8*)&Hbuf[(hrow0 + mlane) * HSTRIDE + kb * 32 + q * 8];
            pc = mfma16(ha, pb[kb], pc);
        }
        if (mlane < 5) {
            #pragma unroll
            for (int r = 0; r < 4; ++r) {
                const int row = q * 4 + r;       // D layout: row=q*4+r, col=mlane (verified)
                out[(m0 + hrow0 + row) * 5 + mlane] = pc[r] + bpv;
            }
        }
    }

    // ---- phase 2: levels 2..7, in-place LDS halving; proj -> outbox ----
    int Mprev = 64;
    #pragma unroll 1
    for (int j = 2; j <= 7; ++j) {
        const int Mnew   = Mprev >> 1;
        const int chunks = (Mnew + 15) >> 4;
        const int obase  = 64 - (256 >> j);      // outbox row base for level j
        for (int c = 0; c < chunks; ++c) {
            f16x8 af[8];
            #pragma unroll
            for (int k = 0; k < 8; ++k) {
                const int off  = k * 64 + q * 16;
                const int trow = off >> 8;
                const int ce   = (off & 255) >> 1;
                af[k] = *(const f16x8*)&Hbuf[(32 * c + 2 * mlane + trow) * HSTRIDE + ce];
            }
            __syncthreads();                     // all reads done before writes
            f32x4 acc0 = {}, acc1 = {};
            #pragma unroll
            for (int k = 0; k < 8; ++k) {
                acc0 = mfma16(af[k], wh[0][k], acc0);
                acc1 = mfma16(af[k], wh[1][k], acc1);
            }
            #pragma unroll
            for (int r = 0; r < 4; ++r) {
                float v0 = fmaxf(acc0[r] + bwv[0], 0.f);
                float v1 = fmaxf(acc1[r] + bwv[1], 0.f);
                Hbuf[(c * 16 + q * 4 + r) * HSTRIDE + wave * 32 + mlane]      = (f16_t)v0;
                Hbuf[(c * 16 + q * 4 + r) * HSTRIDE + wave * 32 + 16 + mlane] = (f16_t)v1;
            }
            __syncthreads();                     // writes visible

            const int valid = (Mnew - c * 16 < 16) ? (Mnew - c * 16) : 16;
            if (wave == 0) {                     // proj -> LDS outbox (no global ops)
                f32x4 pc = {};
                #pragma unroll
                for (int kb = 0; kb < 4; ++kb) {
                    const f16x8 ha = *(const f16x8*)&Hbuf[(c * 16 + mlane) * HSTRIDE + kb * 32 + q * 8];
                    pc = mfma16(ha, pb[kb], pc);
                }
                if (mlane < 5) {
                    #pragma unroll
                    for (int r = 0; r < 4; ++r) {
                        const int row = q * 4 + r;
                        if (row < valid)
                            OutB[(obase + c * 16 + row) * 5 + mlane] = pc[r] + bpv;
                    }
                }
            }
        }
        Mprev = Mnew;
    }
    __syncthreads();                             // outbox + Hbuf row 0 final

    // ---- flush outbox: 63 rows x 5, coalesced-ish ----
    for (int t2 = tid; t2 < 315; t2 += 256) {
        const int lrow = t2 / 5;
        const int cls  = t2 - lrow * 5;
        int j, i;
        if      (lrow < 32) { j = 2; i = lrow;      }
        else if (lrow < 48) { j = 3; i = lrow - 32; }
        else if (lrow < 56) { j = 4; i = lrow - 48; }
        else if (lrow < 60) { j = 5; i = lrow - 56; }
        else if (lrow < 62) { j = 6; i = lrow - 60; }
        else                { j = 7; i = 0;         }
        const size_t grow = (size_t)256 * (1024 - (2048 >> j))
                          + (size_t)tree * (1024 >> j) + (size_t)e * (128 >> j) + i;
        out[grow * 5 + cls] = OutB[t2];
    }

    if (tid < 16)
        *(uint4*)&Q[(size_t)blockIdx.x * 128 + tid * 8] = *(const uint4*)&Hbuf[tid * 8];
}

// ---------------- top 3 levels (8 eighth-roots -> 4 -> 2 -> 1), fp32 ----------------
__global__ __launch_bounds__(128, 4)
void rnn_top_kernel(const f16_t* __restrict__ Q,
                    const float* __restrict__ W,
                    const float* __restrict__ bW,
                    const float* __restrict__ P,
                    const float* __restrict__ bP,
                    float* __restrict__ out)
{
    __shared__ float qs[1024];
    __shared__ float hs[896];    // [0,512): level-8 nodes, [512,768): level-9, [768,896): root
    const int t    = threadIdx.x;
    const int tree = blockIdx.x;

    #pragma unroll
    for (int i = 0; i < 8; ++i)
        qs[t + i * 128] = (float)Q[(size_t)tree * 1024 + t + i * 128];
    __syncthreads();

    const float* wr = W + t * 256;

    // level 8: 4 nodes from 8 eighth-roots
    float s8[4];
    #pragma unroll
    for (int n = 0; n < 4; ++n) s8[n] = bW[t];
    for (int k = 0; k < 256; k += 4) {
        const float4 wv = *(const float4*)(wr + k);
        #pragma unroll
        for (int n = 0; n < 4; ++n) {
            const float* qb = qs + n * 256 + k;
            s8[n] += wv.x * qb[0] + wv.y * qb[1] + wv.z * qb[2] + wv.w * qb[3];
        }
    }
    #pragma unroll
    for (int n = 0; n < 4; ++n) hs[n * 128 + t] = fmaxf(s8[n], 0.f);
    __syncthreads();

    // level 9: 2 nodes
    float s9[2];
    s9[0] = s9[1] = bW[t];
    for (int k = 0; k < 256; k += 4) {
        const float4 wv = *(const float4*)(wr + k);
        #pragma unroll
        for (int m = 0; m < 2; ++m) {
            const float* hb = hs + m * 256 + k;
            s9[m] += wv.x * hb[0] + wv.y * hb[1] + wv.z * hb[2] + wv.w * hb[3];
        }
    }
    hs[512 + t] = fmaxf(s9[0], 0.f);
    hs[640 + t] = fmaxf(s9[1], 0.f);
    __syncthreads();

    // level 10: root
    float s10 = bW[t];
    for (int k = 0; k < 256; k += 4) {
        const float4 wv = *(const float4*)(wr + k);
        const float* hb = hs + 512 + k;
        s10 += wv.x * hb[0] + wv.y * hb[1] + wv.z * hb[2] + wv.w * hb[3];
    }
    hs[768 + t] = fmaxf(s10, 0.f);
    __syncthreads();

    // projections: 7 nodes x 5 classes
    if (t < 35) {
        const int node = t / 5, c = t % 5;
        float s = bP[c];
        const float* hb = hs + node * 128;
        for (int k = 0; k < 128; ++k) s += hb[k] * P[c * 128 + k];
        size_t row;
        if (node < 4)      row = 260096 + (size_t)tree * 4 + node;        // level 8 (n=4/tree)
        else if (node < 6) row = 261120 + (size_t)tree * 2 + (node - 4);  // level 9 (n=2/tree)
        else               row = 261632 + (size_t)tree;                   // level 10 root
        out[row * 5 + c] = s;
    }
}

extern "C" void kernel_launch(void* const* d_in, const int* in_sizes, int n_in,
                              void* d_out, int out_size, void* d_ws, size_t ws_size,
                              hipStream_t stream) {
    const float* leaves = (const float*)d_in[0];   // [256,1024,128] fp32
    const float* W      = (const float*)d_in[1];   // [128,256] fp32
    const float* bW     = (const float*)d_in[2];   // [128] fp32
    const float* P      = (const float*)d_in[3];   // [5,128] fp32
    const float* bP     = (const float*)d_in[4];   // [5] fp32
    float* out = (float*)d_out;                    // [256*1023, 5] fp32

    // ws layout (f16 elems): Wh 32768 | Ph 1024 | Q 262144  (~592 KB)
    f16_t* Wh = (f16_t*)d_ws;
    f16_t* Ph = Wh + 32768;
    f16_t* Q  = Wh + 32768 + 1024;

    prep_kernel<<<dim3(129), dim3(256), 0, stream>>>(W, P, Wh, Ph);
    forest_kernel<<<dim3(2048), dim3(256), 0, stream>>>(leaves, Wh, Ph, bW, bP, Q, out);
    rnn_top_kernel<<<dim3(256), dim3(128), 0, stream>>>(Q, W, bW, P, bP, out);
}

// Round 6
// 225.180 us; speedup vs baseline: 1.1880x; 1.1880x over previous
//
#include <hip/hip_runtime.h>
#include <hip/hip_bf16.h>
#include <hip/hip_fp16.h>

// RecursiveNN forest bottom-up pass, fp32 in / fp32 out.
// forest_kernel: one block per EIGHTH-tree (64 level-1 pair-rows).
// Round-5 lesson: direct-global MFMA fragments scatter (64 lines/inst) ->
// REVERTED to round-4 coalesced Arena preload (known 66 us). This round
// attacks per-block serialization (round-4 had 18 barriers/block):
//   - ping-pong level buffers inside the Arena: every level writes rows
//     disjoint from its valid reads -> ONE barrier per level-step
//   - phase 1: chunks 0-1 -> HB2 side buffer, mid-barrier frees Arena
//     rows 0-31, chunks 2-3 -> Arena rows 0-31
//   - ALL projections (incl. level 1) -> LDS outbox, single flush at end:
//     zero global ops inside the barrier path
//   - proj runs on a rotating wave, overlapped with next level's MFMAs
// 10 barriers/block (was 18), LDS 46.1 KB -> 3 blocks/CU.
// Junk-row note: level-steps always read/write 16-row frames; rows beyond
// `valid` are garbage but provably never overlap valid reads (checked per
// level) and garbage D-rows are masked at proj/store time.
// prep converts W/P to f16 once. rnn_top: top 3 levels fp32 (verified).

typedef _Float16 f16_t;
typedef _Float16 f16x4 __attribute__((ext_vector_type(4)));
typedef _Float16 f16x8 __attribute__((ext_vector_type(8)));
typedef float f32x4 __attribute__((ext_vector_type(4)));

#define HSTRIDE 136   // f16 elems per row slot: 272 B, 16B-aligned

static __device__ __forceinline__ f32x4 mfma16(f16x8 a, f16x8 b, f32x4 c) {
    return __builtin_amdgcn_mfma_f32_16x16x32_f16(a, b, c, 0, 0, 0);
}

// One-shot: W [128,256] fp32 -> fp16 Wh; P [5,128] fp32 -> fp16 Ph.
__global__ void prep_kernel(const float* __restrict__ W, const float* __restrict__ P,
                            f16_t* __restrict__ Wh, f16_t* __restrict__ Ph) {
    if (blockIdx.x < 128) {
        const int i = blockIdx.x * 256 + threadIdx.x;
        Wh[i] = (f16_t)W[i];
    } else {
        for (int i = threadIdx.x; i < 640; i += 256) Ph[i] = (f16_t)P[i];
    }
}

// ---------------- fused levels 1..7 for one 64-pair-row eighth-tree ----------------
__global__ __launch_bounds__(256, 2)
void forest_kernel(const float* __restrict__ leaves,
                   const f16_t* __restrict__ Wh,
                   const f16_t* __restrict__ Ph,
                   const float* __restrict__ bW,
                   const float* __restrict__ bP,
                   f16_t* __restrict__ Q,          // [2048,128] eighth-roots
                   float* __restrict__ out)
{
    __shared__ f16_t AR[128 * HSTRIDE];          // 34816 B: leaf arena, then ping-pong H
    __shared__ f16_t HB2[32 * HSTRIDE];          // 8704 B: level-1 H rows 0-31
    __shared__ float OutB[640];                  // 2560 B: proj outbox, 127 rows x 5

    const int tid   = threadIdx.x;
    const int wave  = tid >> 6;
    const int lane  = tid & 63;
    const int mlane = lane & 15;
    const int q     = lane >> 4;
    const int tree  = blockIdx.x >> 3;
    const int e     = blockIdx.x & 7;
    const float* leafbase = leaves + (size_t)blockIdx.x * 16384;

    // W b-frags (gemm_bt, verified): lane holds W[col][k*32 + q*8 + e]
    f16x8 wh[2][8];
    float bwv[2];
    #pragma unroll
    for (int n = 0; n < 2; ++n) {
        const int col = wave * 32 + n * 16 + mlane;
        bwv[n] = bW[col];
        #pragma unroll
        for (int k = 0; k < 8; ++k)
            wh[n][k] = *(const f16x8*)&Wh[col * 256 + k * 32 + q * 8];
    }

    // P b-frags, N padded 5->16 (zero rows for mlane>=5)
    f16x8 pb[4] = {};
    if (mlane < 5) {
        #pragma unroll
        for (int kb = 0; kb < 4; ++kb)
            pb[kb] = *(const f16x8*)&Ph[mlane * 128 + kb * 32 + q * 8];
    }
    const float bpv = (mlane < 5) ? bP[mlane] : 0.f;

    // ---- whole-block leaf preload: 64 KB fp32 -> f16 arena, 2 batches ----
    #pragma unroll
    for (int b = 0; b < 2; ++b) {
        float4 t[8];
        #pragma unroll
        for (int r = 0; r < 8; ++r)
            t[r] = ((const float4*)leafbase)[tid + (b * 8 + r) * 256];
        #pragma unroll
        for (int r = 0; r < 8; ++r) {
            const int idx = tid + (b * 8 + r) * 256;   // 4096 float4 = 128 leaf rows
            const int row = idx >> 5;
            const int c4  = idx & 31;
            f16x4 t4 = { (f16_t)t[r].x, (f16_t)t[r].y, (f16_t)t[r].z, (f16_t)t[r].w };
            *(f16x4*)&AR[row * HSTRIDE + c4 * 4] = t4;
        }
    }

    // one 16-output-row level step: read 32 src rows (frag pattern), MFMA,
    // write 16 dst rows (always full frame; junk rows masked downstream)
    auto level_step = [&](const f16_t* src, f16_t* dst) {
        f16x8 af[8];
        #pragma unroll
        for (int k = 0; k < 8; ++k) {
            const int off  = k * 64 + q * 16;    // byte offset in 512B pair-row
            const int trow = off >> 8;
            const int ce   = (off & 255) >> 1;
            af[k] = *(const f16x8*)&src[(2 * mlane + trow) * HSTRIDE + ce];
        }
        f32x4 acc0 = {}, acc1 = {};
        #pragma unroll
        for (int k = 0; k < 8; ++k) {
            acc0 = mfma16(af[k], wh[0][k], acc0);
            acc1 = mfma16(af[k], wh[1][k], acc1);
        }
        #pragma unroll
        for (int r = 0; r < 4; ++r) {
            float v0 = fmaxf(acc0[r] + bwv[0], 0.f);
            float v1 = fmaxf(acc1[r] + bwv[1], 0.f);
            dst[(q * 4 + r) * HSTRIDE + wave * 32 + mlane]      = (f16_t)v0;
            dst[(q * 4 + r) * HSTRIDE + wave * 32 + 16 + mlane] = (f16_t)v1;
        }
    };

    // proj of 16 H rows at hb -> OutB rows [orow0, orow0+valid)
    auto proj_to_outb = [&](const f16_t* hb, int orow0, int valid) {
        f32x4 pc = {};
        #pragma unroll
        for (int kb = 0; kb < 4; ++kb) {
            const f16x8 ha = *(const f16x8*)&hb[mlane * HSTRIDE + kb * 32 + q * 8];
            pc = mfma16(ha, pb[kb], pc);
        }
        if (mlane < 5) {
            #pragma unroll
            for (int r = 0; r < 4; ++r) {
                const int row = q * 4 + r;       // D layout: row=q*4+r, col=mlane (verified)
                if (row < valid) OutB[(orow0 + row) * 5 + mlane] = pc[r] + bpv;
            }
        }
    };

    __syncthreads();                                           // B1: arena visible

    // ---- phase 1: level 1 (64 rows out). c0,c1 -> HB2; c2,c3 -> AR[0-31] ----
    level_step(&AR[ 0 * HSTRIDE], &HB2[ 0 * HSTRIDE]);
    level_step(&AR[32 * HSTRIDE], &HB2[16 * HSTRIDE]);
    __syncthreads();                                           // B2: AR[0-63] reads done
    level_step(&AR[64 * HSTRIDE], &AR[ 0 * HSTRIDE]);
    level_step(&AR[96 * HSTRIDE], &AR[16 * HSTRIDE]);
    __syncthreads();                                           // B3: L1 out visible

    // L1 proj: each wave projects one 16-row chunk (overlaps L2 below)
    {
        const f16_t* pbase = (wave < 2) ? &HB2[(wave * 16) * HSTRIDE]
                                        : &AR[((wave - 2) * 16) * HSTRIDE];
        proj_to_outb(pbase, wave * 16, 16);
    }

    // ---- L2 (32 rows out -> AR[32-63]) ----
    level_step(&HB2[0 * HSTRIDE], &AR[32 * HSTRIDE]);          // reads L1 rows 0-31
    level_step(&AR [0 * HSTRIDE], &AR[48 * HSTRIDE]);          // reads L1 rows 32-63
    __syncthreads();                                           // B4
    if (wave == 0) proj_to_outb(&AR[32 * HSTRIDE], 64, 16);
    if (wave == 1) proj_to_outb(&AR[48 * HSTRIDE], 80, 16);

    // ---- L3 (16 rows out -> AR[0-15]) ----
    level_step(&AR[32 * HSTRIDE], &AR[0 * HSTRIDE]);
    __syncthreads();                                           // B5
    if (wave == 2) proj_to_outb(&AR[0 * HSTRIDE], 96, 16);

    // ---- L4 (8 rows out -> AR[16-23], junk to 31) ----
    level_step(&AR[0 * HSTRIDE], &AR[16 * HSTRIDE]);
    __syncthreads();                                           // B6
    if (wave == 3) proj_to_outb(&AR[16 * HSTRIDE], 112, 8);

    // ---- L5 (4 rows out -> AR[24-27], junk to 39) ----
    level_step(&AR[16 * HSTRIDE], &AR[24 * HSTRIDE]);
    __syncthreads();                                           // B7
    if (wave == 0) proj_to_outb(&AR[24 * HSTRIDE], 120, 4);

    // ---- L6 (2 rows out -> AR[28-29], junk to 43) ----
    level_step(&AR[24 * HSTRIDE], &AR[28 * HSTRIDE]);
    __syncthreads();                                           // B8
    if (wave == 1) proj_to_outb(&AR[28 * HSTRIDE], 124, 2);

    // ---- L7 (1 row out -> AR[30], junk to 45) ----
    level_step(&AR[28 * HSTRIDE], &AR[30 * HSTRIDE]);
    __syncthreads();                                           // B9
    if (wave == 2) proj_to_outb(&AR[30 * HSTRIDE], 126, 1);
    __syncthreads();                                           // B10: outbox complete

    // ---- flush outbox: 127 rows x 5 floats, one global-store pass ----
    for (int t2 = tid; t2 < 635; t2 += 256) {
        const int lrow = t2 / 5;
        const int cls  = t2 - lrow * 5;
        int j, i;
        if      (lrow <  64) { j = 1; i = lrow;       }
        else if (lrow <  96) { j = 2; i = lrow - 64;  }
        else if (lrow < 112) { j = 3; i = lrow - 96;  }
        else if (lrow < 120) { j = 4; i = lrow - 112; }
        else if (lrow < 124) { j = 5; i = lrow - 120; }
        else if (lrow < 126) { j = 6; i = lrow - 124; }
        else                 { j = 7; i = 0;          }
        const size_t grow = (size_t)256 * (1024 - (2048 >> j))
                          + (size_t)tree * (1024 >> j) + (size_t)e * (128 >> j) + i;
        out[grow * 5 + cls] = OutB[t2];
    }

    if (tid < 16)
        *(uint4*)&Q[(size_t)blockIdx.x * 128 + tid * 8] = *(const uint4*)&AR[30 * HSTRIDE + tid * 8];
}

// ---------------- top 3 levels (8 eighth-roots -> 4 -> 2 -> 1), fp32 ----------------
__global__ __launch_bounds__(128, 4)
void rnn_top_kernel(const f16_t* __restrict__ Q,
                    const float* __restrict__ W,
                    const float* __restrict__ bW,
                    const float* __restrict__ P,
                    const float* __restrict__ bP,
                    float* __restrict__ out)
{
    __shared__ float qs[1024];
    __shared__ float hs[896];    // [0,512): level-8 nodes, [512,768): level-9, [768,896): root
    const int t    = threadIdx.x;
    const int tree = blockIdx.x;

    #pragma unroll
    for (int i = 0; i < 8; ++i)
        qs[t + i * 128] = (float)Q[(size_t)tree * 1024 + t + i * 128];
    __syncthreads();

    const float* wr = W + t * 256;

    // level 8: 4 nodes from 8 eighth-roots
    float s8[4];
    #pragma unroll
    for (int n = 0; n < 4; ++n) s8[n] = bW[t];
    for (int k = 0; k < 256; k += 4) {
        const float4 wv = *(const float4*)(wr + k);
        #pragma unroll
        for (int n = 0; n < 4; ++n) {
            const float* qb = qs + n * 256 + k;
            s8[n] += wv.x * qb[0] + wv.y * qb[1] + wv.z * qb[2] + wv.w * qb[3];
        }
    }
    #pragma unroll
    for (int n = 0; n < 4; ++n) hs[n * 128 + t] = fmaxf(s8[n], 0.f);
    __syncthreads();

    // level 9: 2 nodes
    float s9[2];
    s9[0] = s9[1] = bW[t];
    for (int k = 0; k < 256; k += 4) {
        const float4 wv = *(const float4*)(wr + k);
        #pragma unroll
        for (int m = 0; m < 2; ++m) {
            const float* hb = hs + m * 256 + k;
            s9[m] += wv.x * hb[0] + wv.y * hb[1] + wv.z * hb[2] + wv.w * hb[3];
        }
    }
    hs[512 + t] = fmaxf(s9[0], 0.f);
    hs[640 + t] = fmaxf(s9[1], 0.f);
    __syncthreads();

    // level 10: root
    float s10 = bW[t];
    for (int k = 0; k < 256; k += 4) {
        const float4 wv = *(const float4*)(wr + k);
        const float* hb = hs + 512 + k;
        s10 += wv.x * hb[0] + wv.y * hb[1] + wv.z * hb[2] + wv.w * hb[3];
    }
    hs[768 + t] = fmaxf(s10, 0.f);
    __syncthreads();

    // projections: 7 nodes x 5 classes
    if (t < 35) {
        const int node = t / 5, c = t % 5;
        float s = bP[c];
        const float* hb = hs + node * 128;
        for (int k = 0; k < 128; ++k) s += hb[k] * P[c * 128 + k];
        size_t row;
        if (node < 4)      row = 260096 + (size_t)tree * 4 + node;        // level 8 (n=4/tree)
        else if (node < 6) row = 261120 + (size_t)tree * 2 + (node - 4);  // level 9 (n=2/tree)
        else               row = 261632 + (size_t)tree;                   // level 10 root
        out[row * 5 + c] = s;
    }
}

extern "C" void kernel_launch(void* const* d_in, const int* in_sizes, int n_in,
                              void* d_out, int out_size, void* d_ws, size_t ws_size,
                              hipStream_t stream) {
    const float* leaves = (const float*)d_in[0];   // [256,1024,128] fp32
    const float* W      = (const float*)d_in[1];   // [128,256] fp32
    const float* bW     = (const float*)d_in[2];   // [128] fp32
    const float* P      = (const float*)d_in[3];   // [5,128] fp32
    const float* bP     = (const float*)d_in[4];   // [5] fp32
    float* out = (float*)d_out;                    // [256*1023, 5] fp32

    // ws layout (f16 elems): Wh 32768 | Ph 1024 | Q 262144  (~592 KB)
    f16_t* Wh = (f16_t*)d_ws;
    f16_t* Ph = Wh + 32768;
    f16_t* Q  = Wh + 32768 + 1024;

    prep_kernel<<<dim3(129), dim3(256), 0, stream>>>(W, P, Wh, Ph);
    forest_kernel<<<dim3(2048), dim3(256), 0, stream>>>(leaves, Wh, Ph, bW, bP, Q, out);
    rnn_top_kernel<<<dim3(256), dim3(128), 0, stream>>>(Q, W, bW, P, bP, out);
}

// Round 7
// 220.486 us; speedup vs baseline: 1.2133x; 1.0213x over previous
//
#include <hip/hip_runtime.h>
#include <hip/hip_bf16.h>
#include <hip/hip_fp16.h>

// RecursiveNN forest bottom-up pass, fp32 in / fp32 out.
// forest_kernel: one block per EIGHTH-tree (64 level-1 pair-rows).
// Round 4-6 evidence: all pipes <13%, occupancy 20-24%, per-step wall ~2us
// invariant vs barrier count -> latency-bound, concurrency-starved.
// Round-7 changes:
//  (1) no HB2: level-1 ping-pongs inside the arena (read window 32c..32c+31,
//      in-step barrier, write 16c..16c+15). LDS 46.1 -> 36.5 KB = 4 blocks/CU.
//  (2) split-K accumulators: 4 independent MFMA chains of 4 per step (was
//      2 chains of 8); proj 2x2 (was 1x4). Halves MFMA dep-stall.
//  (3) all level/proj row windows hand-verified disjoint per segment; junk
//      frame rows are finite stale data, masked at proj by `valid`.
// prep converts W/P to f16 once. rnn_top: top 3 levels fp32 (verified).

typedef _Float16 f16_t;
typedef _Float16 f16x4 __attribute__((ext_vector_type(4)));
typedef _Float16 f16x8 __attribute__((ext_vector_type(8)));
typedef float f32x4 __attribute__((ext_vector_type(4)));

#define HSTRIDE 136   // f16 elems per row slot: 272 B, 16B-aligned

static __device__ __forceinline__ f32x4 mfma16(f16x8 a, f16x8 b, f32x4 c) {
    return __builtin_amdgcn_mfma_f32_16x16x32_f16(a, b, c, 0, 0, 0);
}

// One-shot: W [128,256] fp32 -> fp16 Wh; P [5,128] fp32 -> fp16 Ph.
__global__ void prep_kernel(const float* __restrict__ W, const float* __restrict__ P,
                            f16_t* __restrict__ Wh, f16_t* __restrict__ Ph) {
    if (blockIdx.x < 128) {
        const int i = blockIdx.x * 256 + threadIdx.x;
        Wh[i] = (f16_t)W[i];
    } else {
        for (int i = threadIdx.x; i < 640; i += 256) Ph[i] = (f16_t)P[i];
    }
}

// ---------------- fused levels 1..7 for one 64-pair-row eighth-tree ----------------
__global__ __launch_bounds__(256, 2)
void forest_kernel(const float* __restrict__ leaves,
                   const f16_t* __restrict__ Wh,
                   const f16_t* __restrict__ Ph,
                   const float* __restrict__ bW,
                   const float* __restrict__ bP,
                   f16_t* __restrict__ Q,          // [2048,128] eighth-roots
                   float* __restrict__ out)
{
    __shared__ f16_t AR[128 * HSTRIDE];          // 34816 B: leaf arena + ping-pong H
    __shared__ float OutB[640];                  // 2560 B: proj outbox, 127 rows x 5

    const int tid   = threadIdx.x;
    const int wave  = tid >> 6;
    const int lane  = tid & 63;
    const int mlane = lane & 15;
    const int q     = lane >> 4;
    const int tree  = blockIdx.x >> 3;
    const int e     = blockIdx.x & 7;
    const float* leafbase = leaves + (size_t)blockIdx.x * 16384;

    // W b-frags (gemm_bt, verified): lane holds W[col][k*32 + q*8 + e]
    f16x8 wh[2][8];
    float bwv[2];
    #pragma unroll
    for (int n = 0; n < 2; ++n) {
        const int col = wave * 32 + n * 16 + mlane;
        bwv[n] = bW[col];
        #pragma unroll
        for (int k = 0; k < 8; ++k)
            wh[n][k] = *(const f16x8*)&Wh[col * 256 + k * 32 + q * 8];
    }

    // P b-frags, N padded 5->16 (zero rows for mlane>=5)
    f16x8 pb[4] = {};
    if (mlane < 5) {
        #pragma unroll
        for (int kb = 0; kb < 4; ++kb)
            pb[kb] = *(const f16x8*)&Ph[mlane * 128 + kb * 32 + q * 8];
    }
    const float bpv = (mlane < 5) ? bP[mlane] : 0.f;

    // ---- whole-block leaf preload: 64 KB fp32 -> f16 arena, 2 batches ----
    #pragma unroll
    for (int b = 0; b < 2; ++b) {
        float4 t[8];
        #pragma unroll
        for (int r = 0; r < 8; ++r)
            t[r] = ((const float4*)leafbase)[tid + (b * 8 + r) * 256];
        #pragma unroll
        for (int r = 0; r < 8; ++r) {
            const int idx = tid + (b * 8 + r) * 256;   // 4096 float4 = 128 leaf rows
            const int row = idx >> 5;
            const int c4  = idx & 31;
            f16x4 t4 = { (f16_t)t[r].x, (f16_t)t[r].y, (f16_t)t[r].z, (f16_t)t[r].w };
            *(f16x4*)&AR[row * HSTRIDE + c4 * 4] = t4;
        }
    }

    // read A-frags for a 32-row window at src (verified fragment pattern)
    auto read_frags = [&](const f16_t* src, f16x8* af) {
        #pragma unroll
        for (int k = 0; k < 8; ++k) {
            const int off  = k * 64 + q * 16;    // byte offset in 512B pair-row
            const int trow = off >> 8;
            const int ce   = (off & 255) >> 1;
            af[k] = *(const f16x8*)&src[(2 * mlane + trow) * HSTRIDE + ce];
        }
    };
    // MFMA (split-K: 4 independent chains of 4) + bias + relu -> 16-row frame
    auto mfma_write = [&](const f16x8* af, f16_t* dst) {
        f32x4 a0 = {}, b0 = {}, a1 = {}, b1 = {};
        #pragma unroll
        for (int k = 0; k < 4; ++k) {
            a0 = mfma16(af[k], wh[0][k], a0);
            a1 = mfma16(af[k], wh[1][k], a1);
        }
        #pragma unroll
        for (int k = 4; k < 8; ++k) {
            b0 = mfma16(af[k], wh[0][k], b0);
            b1 = mfma16(af[k], wh[1][k], b1);
        }
        #pragma unroll
        for (int r = 0; r < 4; ++r) {
            float v0 = fmaxf(a0[r] + b0[r] + bwv[0], 0.f);
            float v1 = fmaxf(a1[r] + b1[r] + bwv[1], 0.f);
            dst[(q * 4 + r) * HSTRIDE + wave * 32 + mlane]      = (f16_t)v0;
            dst[(q * 4 + r) * HSTRIDE + wave * 32 + 16 + mlane] = (f16_t)v1;
        }
    };
    // proj of 16 H rows at hb -> OutB rows [orow0, orow0+valid); 2x2 chains
    auto proj_to_outb = [&](const f16_t* hb, int orow0, int valid) {
        f32x4 p0 = {}, p1 = {};
        {
            const f16x8 h0 = *(const f16x8*)&hb[mlane * HSTRIDE + 0 * 32 + q * 8];
            const f16x8 h1 = *(const f16x8*)&hb[mlane * HSTRIDE + 1 * 32 + q * 8];
            const f16x8 h2 = *(const f16x8*)&hb[mlane * HSTRIDE + 2 * 32 + q * 8];
            const f16x8 h3 = *(const f16x8*)&hb[mlane * HSTRIDE + 3 * 32 + q * 8];
            p0 = mfma16(h0, pb[0], p0); p1 = mfma16(h1, pb[1], p1);
            p0 = mfma16(h2, pb[2], p0); p1 = mfma16(h3, pb[3], p1);
        }
        if (mlane < 5) {
            #pragma unroll
            for (int r = 0; r < 4; ++r) {
                const int row = q * 4 + r;       // D layout: row=q*4+r, col=mlane (verified)
                if (row < valid) OutB[(orow0 + row) * 5 + mlane] = p0[r] + p1[r] + bpv;
            }
        }
    };

    __syncthreads();                                           // B1: arena visible

    // ---- level 1: 4 in-arena ping-pong steps ----
    // step c: read rows [32c,32c+32) ; barrier (all reads done) ; write [16c,16c+16)
    #pragma unroll
    for (int c = 0; c < 4; ++c) {
        f16x8 af[8];
        read_frags(&AR[(32 * c) * HSTRIDE], af);
        __syncthreads();                                       // B2..B5
        mfma_write(af, &AR[(16 * c) * HSTRIDE]);
    }
    __syncthreads();                                           // B6: L1 rows 0-63 final

    // ---- Seg A: L1 proj (all waves) + L2 (reads 0-63, writes 64-95) ----
    proj_to_outb(&AR[(16 * wave) * HSTRIDE], 16 * wave, 16);
    {
        f16x8 af[8];
        read_frags(&AR[0], af);
        mfma_write(af, &AR[64 * HSTRIDE]);
        read_frags(&AR[32 * HSTRIDE], af);
        mfma_write(af, &AR[80 * HSTRIDE]);
    }
    __syncthreads();                                           // B7

    // ---- Seg B: L2 proj + L3 (reads 64-95, writes 0-15) ----
    if (wave == 0) proj_to_outb(&AR[64 * HSTRIDE], 64, 16);
    if (wave == 1) proj_to_outb(&AR[80 * HSTRIDE], 80, 16);
    { f16x8 af[8]; read_frags(&AR[64 * HSTRIDE], af); mfma_write(af, &AR[0]); }
    __syncthreads();                                           // B8

    // ---- Seg C: L3 proj + L4 (reads 0-31, writes 32-47, valid 8) ----
    if (wave == 2) proj_to_outb(&AR[0], 96, 16);
    { f16x8 af[8]; read_frags(&AR[0], af); mfma_write(af, &AR[32 * HSTRIDE]); }
    __syncthreads();                                           // B9

    // ---- Seg D: L4 proj + L5 (reads 32-63, writes 0-15, valid 4) ----
    if (wave == 3) proj_to_outb(&AR[32 * HSTRIDE], 112, 8);
    { f16x8 af[8]; read_frags(&AR[32 * HSTRIDE], af); mfma_write(af, &AR[0]); }
    __syncthreads();                                           // B10

    // ---- Seg E: L5 proj + L6 (reads 0-31, writes 32-47, valid 2) ----
    if (wave == 0) proj_to_outb(&AR[0], 120, 4);
    { f16x8 af[8]; read_frags(&AR[0], af); mfma_write(af, &AR[32 * HSTRIDE]); }
    __syncthreads();                                           // B11

    // ---- Seg F: L6 proj + L7 (reads 32-63, writes 0-15, valid 1) ----
    if (wave == 1) proj_to_outb(&AR[32 * HSTRIDE], 124, 2);
    { f16x8 af[8]; read_frags(&AR[32 * HSTRIDE], af); mfma_write(af, &AR[0]); }
    __syncthreads();                                           // B12

    // ---- Seg G: L7 proj + Q store (row 0 = eighth-root) ----
    if (wave == 2) proj_to_outb(&AR[0], 126, 1);
    if (tid < 16)
        *(uint4*)&Q[(size_t)blockIdx.x * 128 + tid * 8] = *(const uint4*)&AR[tid * 8];
    __syncthreads();                                           // B13: outbox complete

    // ---- flush outbox: 127 rows x 5 floats, one global-store pass ----
    for (int t2 = tid; t2 < 635; t2 += 256) {
        const int lrow = t2 / 5;
        const int cls  = t2 - lrow * 5;
        int j, i;
        if      (lrow <  64) { j = 1; i = lrow;       }
        else if (lrow <  96) { j = 2; i = lrow - 64;  }
        else if (lrow < 112) { j = 3; i = lrow - 96;  }
        else if (lrow < 120) { j = 4; i = lrow - 112; }
        else if (lrow < 124) { j = 5; i = lrow - 120; }
        else if (lrow < 126) { j = 6; i = lrow - 124; }
        else                 { j = 7; i = 0;          }
        const size_t grow = (size_t)256 * (1024 - (2048 >> j))
                          + (size_t)tree * (1024 >> j) + (size_t)e * (128 >> j) + i;
        out[grow * 5 + cls] = OutB[t2];
    }
}

// ---------------- top 3 levels (8 eighth-roots -> 4 -> 2 -> 1), fp32 ----------------
__global__ __launch_bounds__(128, 4)
void rnn_top_kernel(const f16_t* __restrict__ Q,
                    const float* __restrict__ W,
                    const float* __restrict__ bW,
                    const float* __restrict__ P,
                    const float* __restrict__ bP,
                    float* __restrict__ out)
{
    __shared__ float qs[1024];
    __shared__ float hs[896];    // [0,512): level-8 nodes, [512,768): level-9, [768,896): root
    const int t    = threadIdx.x;
    const int tree = blockIdx.x;

    #pragma unroll
    for (int i = 0; i < 8; ++i)
        qs[t + i * 128] = (float)Q[(size_t)tree * 1024 + t + i * 128];
    __syncthreads();

    const float* wr = W + t * 256;

    // level 8: 4 nodes from 8 eighth-roots
    float s8[4];
    #pragma unroll
    for (int n = 0; n < 4; ++n) s8[n] = bW[t];
    for (int k = 0; k < 256; k += 4) {
        const float4 wv = *(const float4*)(wr + k);
        #pragma unroll
        for (int n = 0; n < 4; ++n) {
            const float* qb = qs + n * 256 + k;
            s8[n] += wv.x * qb[0] + wv.y * qb[1] + wv.z * qb[2] + wv.w * qb[3];
        }
    }
    #pragma unroll
    for (int n = 0; n < 4; ++n) hs[n * 128 + t] = fmaxf(s8[n], 0.f);
    __syncthreads();

    // level 9: 2 nodes
    float s9[2];
    s9[0] = s9[1] = bW[t];
    for (int k = 0; k < 256; k += 4) {
        const float4 wv = *(const float4*)(wr + k);
        #pragma unroll
        for (int m = 0; m < 2; ++m) {
            const float* hb = hs + m * 256 + k;
            s9[m] += wv.x * hb[0] + wv.y * hb[1] + wv.z * hb[2] + wv.w * hb[3];
        }
    }
    hs[512 + t] = fmaxf(s9[0], 0.f);
    hs[640 + t] = fmaxf(s9[1], 0.f);
    __syncthreads();

    // level 10: root
    float s10 = bW[t];
    for (int k = 0; k < 256; k += 4) {
        const float4 wv = *(const float4*)(wr + k);
        const float* hb = hs + 512 + k;
        s10 += wv.x * hb[0] + wv.y * hb[1] + wv.z * hb[2] + wv.w * hb[3];
    }
    hs[768 + t] = fmaxf(s10, 0.f);
    __syncthreads();

    // projections: 7 nodes x 5 classes
    if (t < 35) {
        const int node = t / 5, c = t % 5;
        float s = bP[c];
        const float* hb = hs + node * 128;
        for (int k = 0; k < 128; ++k) s += hb[k] * P[c * 128 + k];
        size_t row;
        if (node < 4)      row = 260096 + (size_t)tree * 4 + node;        // level 8 (n=4/tree)
        else if (node < 6) row = 261120 + (size_t)tree * 2 + (node - 4);  // level 9 (n=2/tree)
        else               row = 261632 + (size_t)tree;                   // level 10 root
        out[row * 5 + c] = s;
    }
}

extern "C" void kernel_launch(void* const* d_in, const int* in_sizes, int n_in,
                              void* d_out, int out_size, void* d_ws, size_t ws_size,
                              hipStream_t stream) {
    const float* leaves = (const float*)d_in[0];   // [256,1024,128] fp32
    const float* W      = (const float*)d_in[1];   // [128,256] fp32
    const float* bW     = (const float*)d_in[2];   // [128] fp32
    const float* P      = (const float*)d_in[3];   // [5,128] fp32
    const float* bP     = (const float*)d_in[4];   // [5] fp32
    float* out = (float*)d_out;                    // [256*1023, 5] fp32

    // ws layout (f16 elems): Wh 32768 | Ph 1024 | Q 262144  (~592 KB)
    f16_t* Wh = (f16_t*)d_ws;
    f16_t* Ph = Wh + 32768;
    f16_t* Q  = Wh + 32768 + 1024;

    prep_kernel<<<dim3(129), dim3(256), 0, stream>>>(W, P, Wh, Ph);
    forest_kernel<<<dim3(2048), dim3(256), 0, stream>>>(leaves, Wh, Ph, bW, bP, Q, out);
    rnn_top_kernel<<<dim3(256), dim3(128), 0, stream>>>(Q, W, bW, P, bP, out);
}